// Round 1
// baseline (137.155 us; speedup 1.0000x reference)
//
#include <hip/hip_runtime.h>
#include <hip/hip_fp16.h>

// ---------------------------------------------------------------------------
// B=8, N=1024, F=320, H=5 (heads collapse: at = (Q·K^T)/8)
// R16: fuse G2 + topk/softmax + G4 into ONE kernel (fused_attn).
//   Block = 32 query rows of one batch; grid 256 (=1/CU), 512 thr (2 w/SIMD).
//   - 32x1024 `at` strip lives in LDS (fp16, XOR-swizzled) -> no at/attn HBM.
//   - batch = blockIdx.x & 7 -> per-batch XCD L2 affinity; K_b and hW_b
//     (640 KB each) streamed from L2 per block.
//   - PV GEMM: 2-way K-split across wave halves + one 40 KB LDS reduction.
//   Numerics: at accumulation k-ascending (bit-identical to R15), same fp16
//   conversion, same radix topk, same softmax; only G4 k-split reassociates.
// Pipeline: prep_all -> g1_combined (hWT + Q/K) -> fused_attn.
// ---------------------------------------------------------------------------

typedef __attribute__((ext_vector_type(8))) _Float16 half8;
typedef __attribute__((ext_vector_type(4))) float f32x4;

// ---- stage a (nrow16*16) x 32 fp16 tile into LDS, K-chunk XOR-swizzled -----
// LDS slot s of row r holds global chunk s ^ ((r>>1)&3). global_load_lds dest
// is the mandatory uniform base + lane*16B; only the global SOURCE is
// permuted (stays 64B coalesced).
__device__ __forceinline__ void stage_tile(const __half* g, __half* lds,
                                           int nrow16, int ld, int wave, int lane) {
    const int r = lane >> 2;
    const int c = ((lane & 3) ^ ((lane >> 3) & 3)) * 8;  // swizzled chunk
    for (int i = wave; i < nrow16; i += 4) {
        const __half* src = g + (long)(i * 16 + r) * ld + c;
        __builtin_amdgcn_global_load_lds(
            (const __attribute__((address_space(1))) unsigned int*)src,
            (__attribute__((address_space(3))) unsigned int*)(lds + i * 512),
            16, 0, 0);
    }
}

// 8-wave variant for the fused kernel (512 threads)
__device__ __forceinline__ void stage_tile8(const __half* g, __half* lds,
                                            int nrow16, int ld, int wave, int lane) {
    const int r = lane >> 2;
    const int c = ((lane & 3) ^ ((lane >> 3) & 3)) * 8;
    for (int i = wave; i < nrow16; i += 8) {
        const __half* src = g + (long)(i * 16 + r) * ld + c;
        __builtin_amdgcn_global_load_lds(
            (const __attribute__((address_space(1))) unsigned int*)src,
            (__attribute__((address_space(3))) unsigned int*)(lds + i * 512),
            16, 0, 0);
    }
}

// ---------------------------------------------------------------------------
// 128x128 NT fp16 dbuf GEMM body, CH=2 (BK=64), runtime bx/by. K=320 -> 5
// barrier rounds. Buffer: [A c0][A c1][B c0][B c1], 4096 halfs each.
// EPI 1: +bqk, deinterleave -> Q,K fp16.  EPI 2: fp16 store (hWT, ldc=8192).
// ---------------------------------------------------------------------------
template <int EPI>
__device__ __forceinline__ void gemm_body(
    const __half* __restrict__ A, const __half* __restrict__ B,
    void* __restrict__ C, void* __restrict__ C2, const float* __restrict__ bias,
    int lda, int ldb, int ldc, int bx, int by, __half* smem)
{
    constexpr int BUF = 16384;  // (4096+4096)*2 halfs
    const int tid  = threadIdx.x;
    const int lane = tid & 63;
    const int wave = tid >> 6;
    const int wm   = wave >> 1;
    const int wn   = wave & 1;

    const __half* Ab = A + (long)by * 128 * lda;
    const __half* Bb = B + (long)bx * 128 * ldb;

    f32x4 acc[4][4];
    #pragma unroll
    for (int i = 0; i < 4; ++i)
        #pragma unroll
        for (int j = 0; j < 4; ++j) acc[i][j] = (f32x4){0.f, 0.f, 0.f, 0.f};

    const int lrow = lane & 15;
    const int quad = lane >> 4;
    const int swz = (quad ^ ((lrow >> 1) & 3)) * 8;

    #pragma unroll
    for (int c = 0; c < 2; ++c) {
        stage_tile(Ab + c * 32, smem + c * 4096, 8, lda, wave, lane);
        stage_tile(Bb + c * 32, smem + 8192 + c * 4096, 8, ldb, wave, lane);
    }

    for (int it = 0; it < 5; ++it) {
        __syncthreads();
        if (it + 1 < 5) {
            __half* nb = smem + ((it + 1) & 1) * BUF;
            const int k1 = (it + 1) * 64;
            #pragma unroll
            for (int c = 0; c < 2; ++c) {
                stage_tile(Ab + k1 + c * 32, nb + c * 4096, 8, lda, wave, lane);
                stage_tile(Bb + k1 + c * 32, nb + 8192 + c * 4096, 8, ldb, wave, lane);
            }
        }
        const __half* buf = smem + (it & 1) * BUF;
        #pragma unroll
        for (int c = 0; c < 2; ++c) {
            const __half* pA = buf + c * 4096 + (wm * 64 + lrow) * 32 + swz;
            const __half* pB = buf + 8192 + c * 4096 + (wn * 64 + lrow) * 32 + swz;
            half8 ah[4], bh[4];
            #pragma unroll
            for (int mt = 0; mt < 4; ++mt) ah[mt] = *(const half8*)(pA + mt * 512);
            #pragma unroll
            for (int nt = 0; nt < 4; ++nt) bh[nt] = *(const half8*)(pB + nt * 512);
            #pragma unroll
            for (int mt = 0; mt < 4; ++mt)
                #pragma unroll
                for (int nt = 0; nt < 4; ++nt)
                    acc[mt][nt] = __builtin_amdgcn_mfma_f32_16x16x32_f16(
                        ah[mt], bh[nt], acc[mt][nt], 0, 0, 0);
        }
    }

    const int row_base = by * 128 + wm * 64;
    const int col_base = bx * 128 + wn * 64;
    #pragma unroll
    for (int mt = 0; mt < 4; ++mt)
        #pragma unroll
        for (int nt = 0; nt < 4; ++nt)
            #pragma unroll
            for (int r = 0; r < 4; ++r) {
                const int row = row_base + mt * 16 + quad * 4 + r;
                const int col = col_base + nt * 16 + lrow;
                const float v = acc[mt][nt][r];
                if (EPI == 1) {
                    const float val = v + bias[col];
                    const long idx = (long)row * 320 + (col >> 1);
                    if (col & 1) ((__half*)C2)[idx] = __float2half(val);
                    else         ((__half*)C)[idx]  = __float2half(val);
                } else {
                    ((__half*)C)[(long)row * ldc + col] = __float2half(v);
                }
            }
}

// ---- combined: blocks 0..191 do hWT (64x3 tiles); 192..511 do G1' (5x64) ---
__global__ __launch_bounds__(256) void g1_combined(
    const __half* __restrict__ h16, const __half* __restrict__ wTp,
    const __half* __restrict__ WqkT, __half* __restrict__ hWT,
    __half* __restrict__ Q, __half* __restrict__ Kb,
    const float* __restrict__ bqk)
{
    __shared__ __half smem[2 * 16384];
    const int bx = blockIdx.x;
    if (bx < 192) {
        gemm_body<2>(wTp, h16, hWT, nullptr, nullptr,
                     320, 320, 8192, bx % 64, bx / 64, smem);
    } else {
        const int b = bx - 192;
        gemm_body<1>(h16, WqkT, Q, Kb, bqk,
                     320, 320, 320, b % 5, b / 5, smem);
    }
}

// ---- fused prep: h->fp16 (blocks 0..2559) | Wqk^T | weight^T --------------
__global__ __launch_bounds__(256) void prep_all(
    const float* __restrict__ h, ushort4* __restrict__ h16,
    const float* __restrict__ Wqk, __half* __restrict__ WqkT,
    const float* __restrict__ weight, __half* __restrict__ wTp)
{
    const int bx = blockIdx.x;
    if (bx < 2560) {
        const int i = bx * 256 + threadIdx.x;
        const float4 v = ((const float4*)h)[i];
        ushort4 o;
        o.x = __half_as_ushort(__float2half(v.x));
        o.y = __half_as_ushort(__float2half(v.y));
        o.z = __half_as_ushort(__float2half(v.z));
        o.w = __half_as_ushort(__float2half(v.w));
        h16[i] = o;
        return;
    }
    __shared__ float t[32][33];
    const float* src;
    __half* dst;
    int ldS, ldT, c0, r0;
    if (bx < 2760) {
        const int b = bx - 2560;
        src = Wqk; dst = WqkT; ldS = 640; ldT = 320;
        c0 = (b % 20) * 32; r0 = (b / 20) * 32;
    } else {
        const int b = bx - 2760;
        src = weight; dst = wTp; ldS = 320; ldT = 320;
        c0 = (b % 10) * 32; r0 = (b / 10) * 32;
    }
    const int lx = threadIdx.x & 31, ly = threadIdx.x >> 5;
    #pragma unroll
    for (int i = 0; i < 4; ++i)
        t[ly + 8 * i][lx] = src[(long)(r0 + ly + 8 * i) * ldS + c0 + lx];
    __syncthreads();
    #pragma unroll
    for (int i = 0; i < 4; ++i)
        dst[(long)(c0 + ly + 8 * i) * ldT + r0 + lx] = __float2half(t[lx][ly + 8 * i]);
}

// ---------------------------------------------------------------------------
// fused_attn: per block = 32 query rows of one batch (batch = bid&7 -> XCD).
// Phase A (G2): P[32][1024] = 0.125 * Q_rows @ K_b^T, held in LDS fp16.
//   8 waves each own 64 at-cols; cols processed in 2 halves of 512; K_b
//   streamed as [512][32] k-slices (BK=32, 20 rounds, dbuf).
// Phase B: exact 171st-largest per row (2-pass radix, 16-bit keys) + softmax,
//   entirely in LDS; P overwritten with attn fp16.
// Phase C (G4): out_rows = P @ hW_b + bias. Wave halves split K (0..511 /
//   512..1023), each computes full 32x320 partial; one LDS f32 reduction.
// LDS: P 64 KB + X 84 KB = 148 KB -> 1 block/CU.
// P swizzle: half idx ^= (row&7)<<3 (16B-block XOR) - conflict-free b128
// reads along k for both topk and the PV A-operand.
// ---------------------------------------------------------------------------
__global__ __launch_bounds__(512, 2) void fused_attn(
    const __half* __restrict__ Q, const __half* __restrict__ Kmat,
    const __half* __restrict__ hWT, const float* __restrict__ bias,
    float* __restrict__ out)
{
    __shared__ __half smem[75776];      // 151552 B
    __half* const P = smem;             // 32768 halfs: 32 x 1024 (swizzled)
    __half* const X = smem + 32768;     // 43008 halfs: phase-multiplexed

    const int tid  = threadIdx.x;
    const int lane = tid & 63;
    const int wave = tid >> 6;
    const int lrow = lane & 15;
    const int quad = lane >> 4;
    const int swz  = (quad ^ ((lrow >> 1) & 3)) * 8;

    const int b  = blockIdx.x & 7;          // batch -> XCD affinity
    const int r0 = (blockIdx.x >> 3) * 32;  // query-row base

    const __half* Qb = Q    + (long)(b * 1024 + r0) * 320;
    const __half* Kb = Kmat + (long)b * 327680;
    const __half* Wb = hWT  + (long)b * 1024;

    __half* const Xq = X;            // 10240 halfs: Q tiles (10 x [32][32])
    __half* const XB = X + 10240;    // 2 x 16384 halfs: K dbuf ([512][32])

    // ---------------- Phase A: P = 0.125 * Q @ K^T ----------------
    #pragma unroll
    for (int c = 0; c < 10; ++c)
        stage_tile8(Qb + c * 32, Xq + c * 1024, 2, 320, wave, lane);
    stage_tile8(Kb, XB, 32, 320, wave, lane);   // h=0, ks=0

    f32x4 acc[2][4];
    #pragma unroll
    for (int i = 0; i < 2; ++i)
        #pragma unroll
        for (int j = 0; j < 4; ++j) acc[i][j] = (f32x4){0.f, 0.f, 0.f, 0.f};

    for (int r = 0; r < 20; ++r) {
        __syncthreads();
        if (r + 1 < 20) {
            const int rn = r + 1;
            stage_tile8(Kb + (long)(rn / 10) * 512 * 320 + (rn % 10) * 32,
                        XB + (rn & 1) * 16384, 32, 320, wave, lane);
        }
        const int ks = r % 10;
        const __half* Bt = XB + (r & 1) * 16384;
        const __half* At = Xq + ks * 1024;
        half8 ah[2], bh[4];
        #pragma unroll
        for (int mi = 0; mi < 2; ++mi)
            ah[mi] = *(const half8*)(At + (mi * 16 + lrow) * 32 + swz);
        #pragma unroll
        for (int nf = 0; nf < 4; ++nf)
            bh[nf] = *(const half8*)(Bt + (wave * 64 + nf * 16 + lrow) * 32 + swz);
        #pragma unroll
        for (int mi = 0; mi < 2; ++mi)
            #pragma unroll
            for (int nf = 0; nf < 4; ++nf)
                acc[mi][nf] = __builtin_amdgcn_mfma_f32_16x16x32_f16(
                    ah[mi], bh[nf], acc[mi][nf], 0, 0, 0);
        if (ks == 9) {  // end of a col-half: spill acc to P (fp16, *0.125)
            const int cb = (r / 10) * 512 + wave * 64;
            #pragma unroll
            for (int mi = 0; mi < 2; ++mi)
                #pragma unroll
                for (int nf = 0; nf < 4; ++nf)
                    #pragma unroll
                    for (int rr = 0; rr < 4; ++rr) {
                        const int row = mi * 16 + quad * 4 + rr;
                        const int col = cb + nf * 16 + lrow;
                        P[((row << 10) + col) ^ ((row & 7) << 3)] =
                            __float2half(0.125f * acc[mi][nf][rr]);
                        acc[mi][nf][rr] = 0.f;
                    }
        }
    }

    // ---------------- Phase B: topk + softmax in LDS ----------------
    __syncthreads();                       // P complete; X regions free
    // prefetch first PV k-slices (kh0 buf0 @ X+0, kh1 buf0 @ X+20480)
    stage_tile8(Wb,       X,         20, 8192, wave, lane);
    stage_tile8(Wb + 512, X + 20480, 20, 8192, wave, lane);

    int (*const hist)[256] = (int(*)[256])(X + 10240);   // 8 KB, inside buf1

    for (int j = 0; j < 4; ++j) {
        const int row  = wave * 4 + j;
        const int key8 = (row & 7) << 3;
        const int base = (row << 10) + lane * 16;

        unsigned short vs[16];
        *(uint4*)&vs[0] = *(const uint4*)&P[base ^ key8];
        *(uint4*)&vs[8] = *(const uint4*)&P[(base + 8) ^ key8];

        unsigned key[16];
        #pragma unroll
        for (int i = 0; i < 16; ++i) {
            const unsigned u = vs[i];
            key[i] = (u & 0x8000u) ? ((~u) & 0xFFFFu) : (u | 0x8000u);
        }

        unsigned prefix = 0, pmask = 0;
        int kk = 171;

        #pragma unroll
        for (int pass = 0; pass < 2; ++pass) {
            const int shift = 8 - 8 * pass;
            *(int4*)&hist[wave][lane * 4] = make_int4(0, 0, 0, 0);
            __syncthreads();
            #pragma unroll
            for (int i = 0; i < 16; ++i) {
                if ((key[i] & pmask) == prefix)
                    atomicAdd(&hist[wave][(key[i] >> shift) & 255], 1);
            }
            __syncthreads();
            const int4 hh = *(const int4*)&hist[wave][lane * 4];
            const int s = hh.x + hh.y + hh.z + hh.w;
            int suf = s;
            #pragma unroll
            for (int off = 1; off < 64; off <<= 1) {
                const int o = __shfl_down(suf, off);
                if (lane + off < 64) suf += o;
            }
            const int cgt3 = suf - s;
            const int cgt2 = cgt3 + hh.w;
            const int cgt1 = cgt2 + hh.z;
            const int cgt0 = cgt1 + hh.y;
            int pick = 0x7FFFFFFF;
            if (cgt3 < kk && kk <= cgt3 + hh.w) pick = ((4 * lane + 3) << 16) | (kk - cgt3);
            if (cgt2 < kk && kk <= cgt2 + hh.z) pick = ((4 * lane + 2) << 16) | (kk - cgt2);
            if (cgt1 < kk && kk <= cgt1 + hh.y) pick = ((4 * lane + 1) << 16) | (kk - cgt1);
            if (cgt0 < kk && kk <= cgt0 + hh.x) pick = ((4 * lane + 0) << 16) | (kk - cgt0);
            #pragma unroll
            for (int off = 32; off > 0; off >>= 1) pick = min(pick, __shfl_xor(pick, off));
            const unsigned digit = (unsigned)(pick >> 16);
            kk = pick & 0xFFFF;
            prefix |= digit << shift;
            pmask  |= 0xFFu << shift;
            if (pass == 0) __syncthreads();
        }

        const unsigned short tu = (prefix & 0x8000u) ? (unsigned short)(prefix & 0x7FFFu)
                                                     : (unsigned short)((~prefix) & 0xFFFFu);
        const float thr = __half2float(__ushort_as_half(tu));

        float lg[16];
        float mx = -3.4e38f;
        #pragma unroll
        for (int i = 0; i < 16; ++i) {
            const float v = __half2float(__ushort_as_half(vs[i]));
            const float a = (v < thr) ? -1e-7f : v;
            lg[i] = a * (1.0f / 0.3f);
            mx = fmaxf(mx, lg[i]);
        }
        #pragma unroll
        for (int off = 32; off > 0; off >>= 1) mx = fmaxf(mx, __shfl_xor(mx, off));

        float e[16];
        float sum = 0.f;
        #pragma unroll
        for (int i = 0; i < 16; ++i) { e[i] = __expf(lg[i] - mx); sum += e[i]; }
        #pragma unroll
        for (int off = 32; off > 0; off >>= 1) sum += __shfl_xor(sum, off);
        const float inv = 1.0f / sum;

        unsigned short os[16];
        #pragma unroll
        for (int i = 0; i < 16; ++i) os[i] = __half_as_ushort(__float2half(e[i] * inv));
        *(uint4*)&P[base ^ key8]       = *(const uint4*)&os[0];
        *(uint4*)&P[(base + 8) ^ key8] = *(const uint4*)&os[8];
    }

    // ---------------- Phase C: out = P @ hW_b + bias ----------------
    const int q4 = wave & 3;     // col quarter: 80 out-cols
    const int kh = wave >> 2;    // K half: 0 -> k<512, 1 -> k>=512

    f32x4 acc4[2][5];
    #pragma unroll
    for (int i = 0; i < 2; ++i)
        #pragma unroll
        for (int j = 0; j < 5; ++j) acc4[i][j] = (f32x4){0.f, 0.f, 0.f, 0.f};

    for (int r = 0; r < 16; ++r) {
        __syncthreads();
        if (r + 1 < 16) {
            stage_tile8(Wb + (r + 1) * 32,       X + ((r + 1) & 1) * 10240,
                        20, 8192, wave, lane);
            stage_tile8(Wb + 512 + (r + 1) * 32, X + 20480 + ((r + 1) & 1) * 10240,
                        20, 8192, wave, lane);
        }
        const __half* T = X + kh * 20480 + (r & 1) * 10240;
        const int kk = kh * 512 + r * 32 + quad * 8;
        half8 ah[2], bh[5];
        #pragma unroll
        for (int mi = 0; mi < 2; ++mi) {
            const int row = mi * 16 + lrow;
            ah[mi] = *(const half8*)&P[((row << 10) + kk) ^ ((row & 7) << 3)];
        }
        #pragma unroll
        for (int nf = 0; nf < 5; ++nf)
            bh[nf] = *(const half8*)(T + (q4 * 80 + nf * 16 + lrow) * 32 + swz);
        #pragma unroll
        for (int mi = 0; mi < 2; ++mi)
            #pragma unroll
            for (int nf = 0; nf < 5; ++nf)
                acc4[mi][nf] = __builtin_amdgcn_mfma_f32_16x16x32_f16(
                    ah[mi], bh[nf], acc4[mi][nf], 0, 0, 0);
    }

    __syncthreads();
    float* const red = (float*)X;   // 32 x 320 f32 = 40 KB
    if (kh == 1) {
        #pragma unroll
        for (int mi = 0; mi < 2; ++mi)
            #pragma unroll
            for (int nf = 0; nf < 5; ++nf)
                #pragma unroll
                for (int rr = 0; rr < 4; ++rr)
                    red[(mi * 16 + quad * 4 + rr) * 320 + q4 * 80 + nf * 16 + lrow] =
                        acc4[mi][nf][rr];
    }
    __syncthreads();
    if (kh == 0) {
        #pragma unroll
        for (int mi = 0; mi < 2; ++mi)
            #pragma unroll
            for (int nf = 0; nf < 5; ++nf)
                #pragma unroll
                for (int rr = 0; rr < 4; ++rr) {
                    const int row = mi * 16 + quad * 4 + rr;
                    const int col = q4 * 80 + nf * 16 + lrow;
                    out[(long)(b * 1024 + r0 + row) * 320 + col] =
                        acc4[mi][nf][rr] + red[row * 320 + col] + bias[col];
                }
    }
}

extern "C" void kernel_launch(void* const* d_in, const int* in_sizes, int n_in,
                              void* d_out, int out_size, void* d_ws, size_t ws_size,
                              hipStream_t stream) {
    (void)in_sizes; (void)n_in; (void)out_size; (void)ws_size;

    const float* h      = (const float*)d_in[0];  // 8x1024x320
    const float* Wqk    = (const float*)d_in[1];  // 320x640
    const float* bqk    = (const float*)d_in[2];  // 640
    const float* weight = (const float*)d_in[3];  // 320x320
    const float* bias   = (const float*)d_in[4];  // 320
    float* out = (float*)d_out;                   // 8192x320

    // workspace layout (at/attn eliminated)
    char* p = (char*)d_ws;
    __half* h16  = (__half*)p; p += 2621440L * 2;        // 5 MB
    __half* Q    = (__half*)p; p += 2621440L * 2;        // 5 MB
    __half* Kb   = (__half*)p; p += 2621440L * 2;        // 5 MB
    __half* WqkT = (__half*)p; p += 640L * 320 * 2;      // 400 KB
    __half* wTp  = (__half*)p; p += 384L * 320 * 2;      // padded to 384 rows
    __half* hWT  = (__half*)p; p += 384L * 8192 * 2;     // 6 MB (incl pad rows)

    // --- prep (1 launch): h->fp16, WqkT, wTp ---
    prep_all<<<2860, 256, 0, stream>>>(h, (ushort4*)h16, Wqk, WqkT, weight, wTp);

    // --- combined: hWT (192 blocks) + G1' Q/K (320 blocks), BK=64 ---
    g1_combined<<<512, 256, 0, stream>>>(h16, wTp, WqkT, hWT, Q, Kb, bqk);

    // --- fused G2 + topk/softmax + G4: one block per 32 rows x batch ---
    fused_attn<<<256, 512, 0, stream>>>(Q, Kb, hWT, bias, out);
}